// Round 6
// baseline (522.191 us; speedup 1.0000x reference)
//
#include <hip/hip_runtime.h>

#define N_NODES 50000
#define N_EDGES 800000
#define DIM 64
#define NEG_SLOPE 0.2f
#define NEG_INF (-__builtin_inff())
#define SCAN_NB 196          // ceil(50000/256)
#define XM_NB   3125         // N_NODES/16
#define CNT_NB  782          // ceil(800000/1024)
#define MID_NB  1024         // persistent blocks for scan+scatter (16 waves/CU)

typedef _Float16 half8 __attribute__((ext_vector_type(8)));

// Device-scope barrier across all MID_NB co-resident blocks.
__device__ __forceinline__ void gbar(unsigned* ctr, unsigned target) {
    __threadfence();                       // release: wb dirty L2 (cross-XCD)
    __syncthreads();
    if (threadIdx.x == 0) {
        atomicAdd(ctr, 1u);
        while (__hip_atomic_load(ctr, __ATOMIC_ACQUIRE,
                                 __HIP_MEMORY_SCOPE_AGENT) < target) {}
    }
    __syncthreads();
    __threadfence();                       // acquire: inv stale L2
}

// K1 (fused): blocks [0,XM_NB) compute xm fp16 = x@W + b_msg + b_edge;
// blocks [XM_NB, XM_NB+CNT_NB) do the dst histogram + per-edge rank.
__global__ __launch_bounds__(256) void k_pre(const float* __restrict__ x,
                                             const float* __restrict__ W,
                                             const float* __restrict__ b_msg,
                                             const float* __restrict__ b_edge,
                                             _Float16* __restrict__ xmh,
                                             const int* __restrict__ eidx,
                                             unsigned* __restrict__ cnt,
                                             unsigned short* __restrict__ rank) {
    // Wt transposed with +4 pad: row d at Wt+d*68 (272 B, 16B-aligned; start
    // bank 4d%32 -> b128 reads perfectly bank-balanced). Unpadded would be a
    // 64-way conflict (all lanes on banks 4k..4k+3).
    __shared__ float Wt[DIM * 68];    // 17408 B
    __shared__ float xs[16 * DIM];    // 4096 B
    int tid = threadIdx.x;
    if (blockIdx.x >= XM_NB) {        // ---- histogram part ----
        int e0 = (blockIdx.x - XM_NB) * 1024 + tid;
        #pragma unroll
        for (int j = 0; j < 4; ++j) {
            int e = e0 + j * 256;
            if (e < N_EDGES)
                rank[e] = (unsigned short)atomicAdd(cnt + eidx[N_EDGES + e], 1u);
        }
        return;
    }
    // ---- xm part ----
    int base = blockIdx.x * 16;
    const float4* W4 = (const float4*)W;
    #pragma unroll
    for (int i = 0; i < 4; ++i) {
        int idx = tid + 256 * i;           // float4 index into W[k][d]
        float4 wv = W4[idx];
        int k = idx >> 4, d0 = (idx & 15) * 4;
        Wt[(d0 + 0) * 68 + k] = wv.x;
        Wt[(d0 + 1) * 68 + k] = wv.y;
        Wt[(d0 + 2) * 68 + k] = wv.z;
        Wt[(d0 + 3) * 68 + k] = wv.w;
    }
    ((float4*)xs)[tid] = ((const float4*)(x + (size_t)base * DIM))[tid];
    __syncthreads();

    int w = tid >> 6;
    int d = tid & 63;
    float bias = b_msg[d] + b_edge[d];
    float s0 = bias, s1 = bias, s2 = bias, s3 = bias;
    const float* xr = xs + (w * 4) * DIM;
    const float4* wtp = (const float4*)(Wt + d * 68);
    #pragma unroll
    for (int k0 = 0; k0 < 16; ++k0) {
        float4 wv = wtp[k0];                               // ds_read_b128
        float4 xa = *(const float4*)(xr + k0 * 4);         // broadcast b128
        float4 xb = *(const float4*)(xr + DIM + k0 * 4);
        float4 xc = *(const float4*)(xr + 2 * DIM + k0 * 4);
        float4 xd = *(const float4*)(xr + 3 * DIM + k0 * 4);
        s0 = fmaf(xa.x, wv.x, fmaf(xa.y, wv.y, fmaf(xa.z, wv.z, fmaf(xa.w, wv.w, s0))));
        s1 = fmaf(xb.x, wv.x, fmaf(xb.y, wv.y, fmaf(xb.z, wv.z, fmaf(xb.w, wv.w, s1))));
        s2 = fmaf(xc.x, wv.x, fmaf(xc.y, wv.y, fmaf(xc.z, wv.z, fmaf(xc.w, wv.w, s2))));
        s3 = fmaf(xd.x, wv.x, fmaf(xd.y, wv.y, fmaf(xd.z, wv.z, fmaf(xd.w, wv.w, s3))));
    }
    _Float16* o = xmh + ((size_t)base + w * 4) * DIM + d;
    o[0] = (_Float16)s0;
    o[DIM] = (_Float16)s1;
    o[2 * DIM] = (_Float16)s2;
    o[3 * DIM] = (_Float16)s3;
}

// K2 (persistent): phase A = chunk sums, phase B = scan -> off, phase C =
// CSR scatter. Device-scope counter barriers between phases.
__global__ __launch_bounds__(256) void k_mid(const unsigned* __restrict__ cnt,
                                             unsigned* __restrict__ partial,
                                             unsigned* __restrict__ off,
                                             unsigned* __restrict__ done,
                                             const int* __restrict__ eidx,
                                             const float* __restrict__ eattr,
                                             const unsigned short* __restrict__ rank,
                                             int2* __restrict__ elist) {
    int t = threadIdx.x;
    int b = blockIdx.x;
    int lane = t & 63, w = t >> 6;
    __shared__ unsigned ws[4];
    __shared__ unsigned baseLds;

    // ---- phase A: partial[b] = sum of cnt chunk b ----
    if (b < SCAN_NB) {
        int i = b * 256 + t;
        unsigned v = (i < N_NODES) ? cnt[i] : 0u;
        #pragma unroll
        for (int o = 32; o >= 1; o >>= 1) v += __shfl_xor(v, o, 64);
        if (lane == 0) ws[w] = v;
        __syncthreads();
        if (t == 0) partial[b] = ws[0] + ws[1] + ws[2] + ws[3];
    }
    gbar(done + 0, MID_NB);

    // ---- phase B: off[i] = exclusive scan ----
    if (b < SCAN_NB) {
        unsigned pv = (t < SCAN_NB) ? partial[t] : 0u;
        unsigned inc = pv;
        #pragma unroll
        for (int d = 1; d < 64; d <<= 1) {
            unsigned u = __shfl_up(inc, d, 64);
            if (lane >= d) inc += u;
        }
        if (lane == 63) ws[w] = inc;
        __syncthreads();
        unsigned wadd = 0;
        #pragma unroll
        for (int k = 0; k < 4; ++k) if (k < w) wadd += ws[k];
        if (t == b) baseLds = inc - pv + wadd;
        __syncthreads();
        unsigned bb = baseLds;
        int i = b * 256 + t;
        unsigned v = (i < N_NODES) ? cnt[i] : 0u;
        unsigned inc2 = v;
        #pragma unroll
        for (int d = 1; d < 64; d <<= 1) {
            unsigned u = __shfl_up(inc2, d, 64);
            if (lane >= d) inc2 += u;
        }
        __syncthreads();                 // ws reuse
        if (lane == 63) ws[w] = inc2;
        __syncthreads();
        unsigned wadd2 = 0;
        #pragma unroll
        for (int k = 0; k < 4; ++k) if (k < w) wadd2 += ws[k];
        if (i < N_NODES) off[i] = inc2 - v + wadd2 + bb;
        if (b == 0 && t == 0) off[N_NODES] = N_EDGES;
    }
    gbar(done + 1, MID_NB);

    // ---- phase C: scatter edges into CSR order (no atomics) ----
    for (int e = b * 256 + t; e < N_EDGES; e += MID_NB * 256) {
        int dst = eidx[N_EDGES + e];
        unsigned pos = off[dst] + rank[e];
        elist[pos] = make_int2(eidx[e], __float_as_int(eattr[e]));
    }
}

// K3: wave per destination; 8 groups x 8 lanes; 8 edges per iteration.
// Each group keeps an independent online-softmax state (m, denom, vmax) over
// its strided 1/8 of the edge list; states are merged once at the end.
// Exact: max-aggregation commutes with the uniform positive rescale.
__global__ __launch_bounds__(256) void k_aggregate(const half8* __restrict__ xm8,
                                                   const int2* __restrict__ elist,
                                                   const unsigned* __restrict__ off,
                                                   const float4* __restrict__ W_edge4,
                                                   const float4* __restrict__ att4,
                                                   const float4* __restrict__ x4,
                                                   float4* __restrict__ out4) {
    int node = blockIdx.x * 4 + (threadIdx.x >> 6);
    int lane = threadIdx.x & 63;
    int g = lane >> 3, t = lane & 7;
    unsigned beg = off[node], end = off[node + 1];
    size_t obase = (size_t)node * 16 + 2 * t;
    if (beg == end) {
        if (g == 0) { out4[obase] = x4[obase]; out4[obase + 1] = x4[obase + 1]; }
        return;
    }
    float4 wa = W_edge4[2 * t], wb = W_edge4[2 * t + 1];
    float4 aa = att4[2 * t],    ab = att4[2 * t + 1];
    float we[8] = {wa.x, wa.y, wa.z, wa.w, wb.x, wb.y, wb.z, wb.w};
    float at[8] = {aa.x, aa.y, aa.z, aa.w, ab.x, ab.y, ab.z, ab.w};

    unsigned idx = beg + (unsigned)g;
    bool act = idx < end;
    int2 e = elist[act ? idx : beg];
    half8 h = xm8[(size_t)e.x * 8 + t];

    float m = NEG_INF, denom = 0.f;
    float v[8];
    #pragma unroll
    for (int k = 0; k < 8; ++k) v[k] = 0.f;
    bool first = true;

    for (unsigned b = beg;; b += 8) {
        bool more = (b + 8) < end;         // wave-uniform
        int2 e2; half8 h2; bool a2 = false;
        if (more) {                        // prefetch next 8 edges
            unsigned i2 = b + 8 + (unsigned)g;
            a2 = i2 < end;
            e2 = elist[a2 ? i2 : beg];
            h2 = xm8[(size_t)e2.x * 8 + t];
        }
        float ea = __int_as_float(e.y);
        float msg[8];
        float p = 0.f;
        #pragma unroll
        for (int k = 0; k < 8; ++k) {
            float f = (float)h[k];
            msg[k] = fmaf(ea, we[k], f);
            float lr = fmaxf(msg[k], NEG_SLOPE * msg[k]);   // leaky (slope<1)
            p = fmaf(lr, at[k], p);
        }
        p += __shfl_xor(p, 1, 64);
        p += __shfl_xor(p, 2, 64);
        p += __shfl_xor(p, 4, 64);          // group-uniform logit
        if (first) {
            if (act) {
                m = p; denom = 1.f;
                #pragma unroll
                for (int k = 0; k < 8; ++k) v[k] = msg[k];
            }
            first = false;
        } else if (act) {
            float M = fmaxf(m, p);
            float so = __expf(m - M);
            float sn = __expf(p - M);
            denom = fmaf(denom, so, sn);
            #pragma unroll
            for (int k = 0; k < 8; ++k)
                v[k] = fmaxf(v[k] * so, msg[k] * sn);
            m = M;
        }
        if (!more) break;
        e = e2; h = h2; act = a2;
    }
    // merge the 8 per-group states
    bool has = denom > 0.f;
    float Ms = m;                           // NEG_INF when !has
    Ms = fmaxf(Ms, __shfl_xor(Ms, 8, 64));
    Ms = fmaxf(Ms, __shfl_xor(Ms, 16, 64));
    Ms = fmaxf(Ms, __shfl_xor(Ms, 32, 64));
    float s = has ? __expf(m - Ms) : 0.f;
    float dd = denom * s;
    dd += __shfl_xor(dd, 8, 64);
    dd += __shfl_xor(dd, 16, 64);
    dd += __shfl_xor(dd, 32, 64);
    float gv[8];
    #pragma unroll
    for (int k = 0; k < 8; ++k) {
        float gk = has ? v[k] * s : NEG_INF;
        gk = fmaxf(gk, __shfl_xor(gk, 8, 64));
        gk = fmaxf(gk, __shfl_xor(gk, 16, 64));
        gk = fmaxf(gk, __shfl_xor(gk, 32, 64));
        gv[k] = gk;
    }
    if (g == 0) {
        float inv = 1.0f / (dd + 1e-16f);
        float4 xa = x4[obase], xb = x4[obase + 1];
        float4 r0, r1;
        r0.x = fmaf(gv[0], inv, xa.x);
        r0.y = fmaf(gv[1], inv, xa.y);
        r0.z = fmaf(gv[2], inv, xa.z);
        r0.w = fmaf(gv[3], inv, xa.w);
        r1.x = fmaf(gv[4], inv, xb.x);
        r1.y = fmaf(gv[5], inv, xb.y);
        r1.z = fmaf(gv[6], inv, xb.z);
        r1.w = fmaf(gv[7], inv, xb.w);
        out4[obase] = r0;
        out4[obase + 1] = r1;
    }
}

extern "C" void kernel_launch(void* const* d_in, const int* in_sizes, int n_in,
                              void* d_out, int out_size, void* d_ws, size_t ws_size,
                              hipStream_t stream) {
    const float* x      = (const float*)d_in[0];
    const int*   eidx   = (const int*)d_in[1];     // [2, E] int32
    const float* eattr  = (const float*)d_in[2];
    const float* W_msg  = (const float*)d_in[3];
    const float* b_msg  = (const float*)d_in[4];
    const float* W_edge = (const float*)d_in[5];   // [1, D]
    const float* b_edge = (const float*)d_in[6];
    const float* att    = (const float*)d_in[7];
    float* out = (float*)d_out;

    // Workspace layout:
    //   xmh:     N*64 fp16   6.4 MB
    //   elist:   E int2      6.4 MB
    //   cnt:     N u32       0.2 MB   \ zeroed together
    //   done:    2 u32                /
    //   off:     N+1 u32
    //   partial: SCAN_NB u32
    //   rank:    E u16       1.6 MB
    _Float16*       xmh     = (_Float16*)d_ws;
    int2*           elist   = (int2*)(xmh + (size_t)N_NODES * DIM);
    unsigned*       cnt     = (unsigned*)(elist + N_EDGES);
    unsigned*       done    = cnt + N_NODES;
    unsigned*       off     = done + 2;
    unsigned*       partial = off + N_NODES + 1;
    unsigned short* rank    = (unsigned short*)(partial + SCAN_NB);

    hipMemsetAsync(cnt, 0, ((size_t)N_NODES + 2) * 4, stream);

    k_pre<<<XM_NB + CNT_NB, 256, 0, stream>>>(x, W_msg, b_msg, b_edge, xmh,
                                              eidx, cnt, rank);
    k_mid<<<MID_NB, 256, 0, stream>>>(cnt, partial, off, done, eidx, eattr,
                                      rank, elist);
    k_aggregate<<<N_NODES / 4, 256, 0, stream>>>(
        (const half8*)xmh, elist, off, (const float4*)W_edge,
        (const float4*)att, (const float4*)x, (float4*)out);
}

// Round 7
// 172.939 us; speedup vs baseline: 3.0195x; 3.0195x over previous
//
#include <hip/hip_runtime.h>

#define N_NODES 50000
#define N_EDGES 800000
#define DIM 64
#define NEG_SLOPE 0.2f
#define NEG_INF (-__builtin_inff())
#define SCAN_NB 196          // ceil(50000/256)
#define XM_NB   3125         // N_NODES/16
#define CNT_NB  782          // ceil(800000/1024)

typedef _Float16 half8 __attribute__((ext_vector_type(8)));

// K1 (fused): blocks [0,XM_NB) compute xm fp16 = x@W + b_msg + b_edge;
// blocks [XM_NB, XM_NB+CNT_NB) do the dst histogram + per-edge rank.
__global__ __launch_bounds__(256) void k_pre(const float* __restrict__ x,
                                             const float* __restrict__ W,
                                             const float* __restrict__ b_msg,
                                             const float* __restrict__ b_edge,
                                             _Float16* __restrict__ xmh,
                                             const int* __restrict__ eidx,
                                             unsigned* __restrict__ cnt,
                                             unsigned short* __restrict__ rank) {
    // Wt transposed with +4 pad: row d at Wt+d*68 (272 B, 16B-aligned; start
    // bank 4d%32 -> b128 reads bank-balanced). Unpadded transpose would be a
    // full-wave conflict (all lanes on banks 4k..4k+3).
    __shared__ float Wt[DIM * 68];    // 17408 B
    __shared__ float xs[16 * DIM];    // 4096 B
    int tid = threadIdx.x;
    if (blockIdx.x >= XM_NB) {        // ---- histogram part ----
        int e0 = (blockIdx.x - XM_NB) * 1024 + tid;
        #pragma unroll
        for (int j = 0; j < 4; ++j) {
            int e = e0 + j * 256;
            if (e < N_EDGES)
                rank[e] = (unsigned short)atomicAdd(cnt + eidx[N_EDGES + e], 1u);
        }
        return;
    }
    // ---- xm part ----
    int base = blockIdx.x * 16;
    const float4* W4 = (const float4*)W;
    #pragma unroll
    for (int i = 0; i < 4; ++i) {
        int idx = tid + 256 * i;           // float4 index into W[k][d]
        float4 wv = W4[idx];
        int k = idx >> 4, d0 = (idx & 15) * 4;
        Wt[(d0 + 0) * 68 + k] = wv.x;
        Wt[(d0 + 1) * 68 + k] = wv.y;
        Wt[(d0 + 2) * 68 + k] = wv.z;
        Wt[(d0 + 3) * 68 + k] = wv.w;
    }
    ((float4*)xs)[tid] = ((const float4*)(x + (size_t)base * DIM))[tid];
    __syncthreads();

    int w = tid >> 6;
    int d = tid & 63;
    float bias = b_msg[d] + b_edge[d];
    float s0 = bias, s1 = bias, s2 = bias, s3 = bias;
    const float* xr = xs + (w * 4) * DIM;
    const float4* wtp = (const float4*)(Wt + d * 68);
    #pragma unroll
    for (int k0 = 0; k0 < 16; ++k0) {
        float4 wv = wtp[k0];                               // ds_read_b128
        float4 xa = *(const float4*)(xr + k0 * 4);         // broadcast b128
        float4 xb = *(const float4*)(xr + DIM + k0 * 4);
        float4 xc = *(const float4*)(xr + 2 * DIM + k0 * 4);
        float4 xd = *(const float4*)(xr + 3 * DIM + k0 * 4);
        s0 = fmaf(xa.x, wv.x, fmaf(xa.y, wv.y, fmaf(xa.z, wv.z, fmaf(xa.w, wv.w, s0))));
        s1 = fmaf(xb.x, wv.x, fmaf(xb.y, wv.y, fmaf(xb.z, wv.z, fmaf(xb.w, wv.w, s1))));
        s2 = fmaf(xc.x, wv.x, fmaf(xc.y, wv.y, fmaf(xc.z, wv.z, fmaf(xc.w, wv.w, s2))));
        s3 = fmaf(xd.x, wv.x, fmaf(xd.y, wv.y, fmaf(xd.z, wv.z, fmaf(xd.w, wv.w, s3))));
    }
    _Float16* o = xmh + ((size_t)base + w * 4) * DIM + d;
    o[0] = (_Float16)s0;
    o[DIM] = (_Float16)s1;
    o[2 * DIM] = (_Float16)s2;
    o[3 * DIM] = (_Float16)s3;
}

// K2a: per-block (256-chunk) sums of cnt -> partial[SCAN_NB]
__global__ __launch_bounds__(256) void k_scan1(const unsigned* __restrict__ cnt,
                                               unsigned* __restrict__ partial) {
    int t = threadIdx.x;
    int i = blockIdx.x * 256 + t;
    unsigned v = (i < N_NODES) ? cnt[i] : 0u;
    #pragma unroll
    for (int o = 32; o >= 1; o >>= 1) v += __shfl_xor(v, o, 64);
    __shared__ unsigned ws[4];
    if ((t & 63) == 0) ws[t >> 6] = v;
    __syncthreads();
    if (t == 0) partial[blockIdx.x] = ws[0] + ws[1] + ws[2] + ws[3];
}

// K2b: each block redundantly scans all 196 partials (784 B), then scans its
// own 256-chunk and writes off.
__global__ __launch_bounds__(256) void k_scan23(const unsigned* __restrict__ cnt,
                                                const unsigned* __restrict__ partial,
                                                unsigned* __restrict__ off) {
    int t = threadIdx.x;
    int lane = t & 63, w = t >> 6;
    __shared__ unsigned ws[4];
    __shared__ unsigned baseLds;
    unsigned pv = (t < SCAN_NB) ? partial[t] : 0u;
    unsigned inc = pv;
    #pragma unroll
    for (int d = 1; d < 64; d <<= 1) {
        unsigned u = __shfl_up(inc, d, 64);
        if (lane >= d) inc += u;
    }
    if (lane == 63) ws[w] = inc;
    __syncthreads();
    unsigned wadd = 0;
    #pragma unroll
    for (int k = 0; k < 4; ++k) if (k < w) wadd += ws[k];
    if (t == (int)blockIdx.x) baseLds = inc - pv + wadd;
    __syncthreads();
    unsigned base = baseLds;
    int i = blockIdx.x * 256 + t;
    unsigned v = (i < N_NODES) ? cnt[i] : 0u;
    unsigned inc2 = v;
    #pragma unroll
    for (int d = 1; d < 64; d <<= 1) {
        unsigned u = __shfl_up(inc2, d, 64);
        if (lane >= d) inc2 += u;
    }
    __syncthreads();                 // ws reuse
    if (lane == 63) ws[w] = inc2;
    __syncthreads();
    unsigned wadd2 = 0;
    #pragma unroll
    for (int k = 0; k < 4; ++k) if (k < w) wadd2 += ws[k];
    if (i < N_NODES) off[i] = inc2 - v + wadd2 + base;
    if (blockIdx.x == 0 && t == 0) off[N_NODES] = N_EDGES;
}

// K3: scatter edges into CSR order (no atomics)
__global__ __launch_bounds__(256) void k_scatter(const int* __restrict__ eidx,
                                                 const float* __restrict__ eattr,
                                                 const unsigned* __restrict__ off,
                                                 const unsigned short* __restrict__ rank,
                                                 int2* __restrict__ elist) {
    int e = blockIdx.x * 256 + threadIdx.x;
    if (e >= N_EDGES) return;
    int dst = eidx[N_EDGES + e];
    unsigned pos = off[dst] + rank[e];
    elist[pos] = make_int2(eidx[e], __float_as_int(eattr[e]));
}

// K4: wave per destination; 8 groups x 8 lanes; 8 edges per iteration.
// Each group keeps an independent online-softmax state (m, denom, vmax) over
// its strided 1/8 of the edge list; states are merged once at the end.
// Exact: max-aggregation commutes with the uniform positive rescale.
__global__ __launch_bounds__(256) void k_aggregate(const half8* __restrict__ xm8,
                                                   const int2* __restrict__ elist,
                                                   const unsigned* __restrict__ off,
                                                   const float4* __restrict__ W_edge4,
                                                   const float4* __restrict__ att4,
                                                   const float4* __restrict__ x4,
                                                   float4* __restrict__ out4) {
    int node = blockIdx.x * 4 + (threadIdx.x >> 6);
    int lane = threadIdx.x & 63;
    int g = lane >> 3, t = lane & 7;
    unsigned beg = off[node], end = off[node + 1];
    size_t obase = (size_t)node * 16 + 2 * t;
    if (beg == end) {
        if (g == 0) { out4[obase] = x4[obase]; out4[obase + 1] = x4[obase + 1]; }
        return;
    }
    float4 wa = W_edge4[2 * t], wb = W_edge4[2 * t + 1];
    float4 aa = att4[2 * t],    ab = att4[2 * t + 1];
    float we[8] = {wa.x, wa.y, wa.z, wa.w, wb.x, wb.y, wb.z, wb.w};
    float at[8] = {aa.x, aa.y, aa.z, aa.w, ab.x, ab.y, ab.z, ab.w};

    unsigned idx = beg + (unsigned)g;
    bool act = idx < end;
    int2 e = elist[act ? idx : beg];
    half8 h = xm8[(size_t)e.x * 8 + t];

    float m = NEG_INF, denom = 0.f;
    float v[8];
    #pragma unroll
    for (int k = 0; k < 8; ++k) v[k] = 0.f;
    bool first = true;

    for (unsigned b = beg;; b += 8) {
        bool more = (b + 8) < end;         // wave-uniform
        int2 e2; half8 h2; bool a2 = false;
        if (more) {                        // prefetch next 8 edges
            unsigned i2 = b + 8 + (unsigned)g;
            a2 = i2 < end;
            e2 = elist[a2 ? i2 : beg];
            h2 = xm8[(size_t)e2.x * 8 + t];
        }
        float ea = __int_as_float(e.y);
        float msg[8];
        float p = 0.f;
        #pragma unroll
        for (int k = 0; k < 8; ++k) {
            float f = (float)h[k];
            msg[k] = fmaf(ea, we[k], f);
            float lr = fmaxf(msg[k], NEG_SLOPE * msg[k]);   // leaky (slope<1)
            p = fmaf(lr, at[k], p);
        }
        p += __shfl_xor(p, 1, 64);
        p += __shfl_xor(p, 2, 64);
        p += __shfl_xor(p, 4, 64);          // group-uniform logit
        if (first) {
            if (act) {
                m = p; denom = 1.f;
                #pragma unroll
                for (int k = 0; k < 8; ++k) v[k] = msg[k];
            }
            first = false;
        } else if (act) {
            float M = fmaxf(m, p);
            float so = __expf(m - M);
            float sn = __expf(p - M);
            denom = fmaf(denom, so, sn);
            #pragma unroll
            for (int k = 0; k < 8; ++k)
                v[k] = fmaxf(v[k] * so, msg[k] * sn);
            m = M;
        }
        if (!more) break;
        e = e2; h = h2; act = a2;
    }
    // merge the 8 per-group states
    bool has = denom > 0.f;
    float Ms = m;                           // NEG_INF when !has
    Ms = fmaxf(Ms, __shfl_xor(Ms, 8, 64));
    Ms = fmaxf(Ms, __shfl_xor(Ms, 16, 64));
    Ms = fmaxf(Ms, __shfl_xor(Ms, 32, 64));
    float s = has ? __expf(m - Ms) : 0.f;
    float dd = denom * s;
    dd += __shfl_xor(dd, 8, 64);
    dd += __shfl_xor(dd, 16, 64);
    dd += __shfl_xor(dd, 32, 64);
    float gv[8];
    #pragma unroll
    for (int k = 0; k < 8; ++k) {
        float gk = has ? v[k] * s : NEG_INF;
        gk = fmaxf(gk, __shfl_xor(gk, 8, 64));
        gk = fmaxf(gk, __shfl_xor(gk, 16, 64));
        gk = fmaxf(gk, __shfl_xor(gk, 32, 64));
        gv[k] = gk;
    }
    if (g == 0) {
        float inv = 1.0f / (dd + 1e-16f);
        float4 xa = x4[obase], xb = x4[obase + 1];
        float4 r0, r1;
        r0.x = fmaf(gv[0], inv, xa.x);
        r0.y = fmaf(gv[1], inv, xa.y);
        r0.z = fmaf(gv[2], inv, xa.z);
        r0.w = fmaf(gv[3], inv, xa.w);
        r1.x = fmaf(gv[4], inv, xb.x);
        r1.y = fmaf(gv[5], inv, xb.y);
        r1.z = fmaf(gv[6], inv, xb.z);
        r1.w = fmaf(gv[7], inv, xb.w);
        out4[obase] = r0;
        out4[obase + 1] = r1;
    }
}

extern "C" void kernel_launch(void* const* d_in, const int* in_sizes, int n_in,
                              void* d_out, int out_size, void* d_ws, size_t ws_size,
                              hipStream_t stream) {
    const float* x      = (const float*)d_in[0];
    const int*   eidx   = (const int*)d_in[1];     // [2, E] int32
    const float* eattr  = (const float*)d_in[2];
    const float* W_msg  = (const float*)d_in[3];
    const float* b_msg  = (const float*)d_in[4];
    const float* W_edge = (const float*)d_in[5];   // [1, D]
    const float* b_edge = (const float*)d_in[6];
    const float* att    = (const float*)d_in[7];
    float* out = (float*)d_out;

    // Workspace layout:
    //   xmh:     N*64 fp16   6.4 MB
    //   elist:   E int2      6.4 MB
    //   cnt:     N u32       0.2 MB   -- zeroed
    //   off:     N+1 u32
    //   partial: SCAN_NB u32
    //   rank:    E u16       1.6 MB
    _Float16*       xmh     = (_Float16*)d_ws;
    int2*           elist   = (int2*)(xmh + (size_t)N_NODES * DIM);
    unsigned*       cnt     = (unsigned*)(elist + N_EDGES);
    unsigned*       off     = cnt + N_NODES;
    unsigned*       partial = off + N_NODES + 1;
    unsigned short* rank    = (unsigned short*)(partial + SCAN_NB);

    hipMemsetAsync(cnt, 0, (size_t)N_NODES * 4, stream);

    k_pre<<<XM_NB + CNT_NB, 256, 0, stream>>>(x, W_msg, b_msg, b_edge, xmh,
                                              eidx, cnt, rank);
    k_scan1<<<SCAN_NB, 256, 0, stream>>>(cnt, partial);
    k_scan23<<<SCAN_NB, 256, 0, stream>>>(cnt, partial, off);
    k_scatter<<<N_EDGES / 256, 256, 0, stream>>>(eidx, eattr, off, rank, elist);
    k_aggregate<<<N_NODES / 4, 256, 0, stream>>>(
        (const half8*)xmh, elist, off, (const float4*)W_edge,
        (const float4*)att, (const float4*)x, (float4*)out);
}

// Round 8
// 170.872 us; speedup vs baseline: 3.0560x; 1.0121x over previous
//
#include <hip/hip_runtime.h>

#define N_NODES 50000
#define N_EDGES 800000
#define DIM 64
#define NEG_SLOPE 0.2f
#define NEG_INF (-__builtin_inff())
#define SCAN_NB 196          // ceil(50000/256)
#define XM_NB   3125         // N_NODES/16
#define CNT_NB  782          // ceil(800000/1024)
#define NREP    8            // XCD count — histogram replicas

typedef _Float16 half8 __attribute__((ext_vector_type(8)));

// K1 (fused): blocks [0,XM_NB) compute xm fp16 = x@W + b_msg + b_edge;
// blocks [XM_NB, XM_NB+CNT_NB) do the dst histogram + per-edge rank.
// Histogram is replicated per-XCD (r = blockIdx&7): atomics stay in the
// local L2 instead of bouncing counter lines across 8 non-coherent XCDs
// (round-7 profile: 25 MB of atomic write-back traffic on WRITE_SIZE).
__global__ __launch_bounds__(256) void k_pre(const float* __restrict__ x,
                                             const float* __restrict__ W,
                                             const float* __restrict__ b_msg,
                                             const float* __restrict__ b_edge,
                                             _Float16* __restrict__ xmh,
                                             const int* __restrict__ eidx,
                                             unsigned* __restrict__ cnt2,
                                             unsigned short* __restrict__ rank) {
    __shared__ float Wt[DIM * 68];    // transposed, +4 pad
    __shared__ float xs[16 * DIM];
    int tid = threadIdx.x;
    if (blockIdx.x >= XM_NB) {        // ---- histogram part ----
        int e0 = (blockIdx.x - XM_NB) * 1024 + tid;
        unsigned* mycnt = cnt2 + (size_t)(blockIdx.x & (NREP - 1)) * N_NODES;
        #pragma unroll
        for (int j = 0; j < 4; ++j) {
            int e = e0 + j * 256;
            if (e < N_EDGES)
                rank[e] = (unsigned short)atomicAdd(mycnt + eidx[N_EDGES + e], 1u);
        }
        return;
    }
    // ---- xm part ----
    int base = blockIdx.x * 16;
    const float4* W4 = (const float4*)W;
    #pragma unroll
    for (int i = 0; i < 4; ++i) {
        int idx = tid + 256 * i;           // float4 index into W[k][d]
        float4 wv = W4[idx];
        int k = idx >> 4, d0 = (idx & 15) * 4;
        Wt[(d0 + 0) * 68 + k] = wv.x;
        Wt[(d0 + 1) * 68 + k] = wv.y;
        Wt[(d0 + 2) * 68 + k] = wv.z;
        Wt[(d0 + 3) * 68 + k] = wv.w;
    }
    ((float4*)xs)[tid] = ((const float4*)(x + (size_t)base * DIM))[tid];
    __syncthreads();

    int w = tid >> 6;
    int d = tid & 63;
    float bias = b_msg[d] + b_edge[d];
    float s0 = bias, s1 = bias, s2 = bias, s3 = bias;
    const float* xr = xs + (w * 4) * DIM;
    const float4* wtp = (const float4*)(Wt + d * 68);
    #pragma unroll
    for (int k0 = 0; k0 < 16; ++k0) {
        float4 wv = wtp[k0];
        float4 xa = *(const float4*)(xr + k0 * 4);
        float4 xb = *(const float4*)(xr + DIM + k0 * 4);
        float4 xc = *(const float4*)(xr + 2 * DIM + k0 * 4);
        float4 xd = *(const float4*)(xr + 3 * DIM + k0 * 4);
        s0 = fmaf(xa.x, wv.x, fmaf(xa.y, wv.y, fmaf(xa.z, wv.z, fmaf(xa.w, wv.w, s0))));
        s1 = fmaf(xb.x, wv.x, fmaf(xb.y, wv.y, fmaf(xb.z, wv.z, fmaf(xb.w, wv.w, s1))));
        s2 = fmaf(xc.x, wv.x, fmaf(xc.y, wv.y, fmaf(xc.z, wv.z, fmaf(xc.w, wv.w, s2))));
        s3 = fmaf(xd.x, wv.x, fmaf(xd.y, wv.y, fmaf(xd.z, wv.z, fmaf(xd.w, wv.w, s3))));
    }
    _Float16* o = xmh + ((size_t)base + w * 4) * DIM + d;
    o[0] = (_Float16)s0;
    o[DIM] = (_Float16)s1;
    o[2 * DIM] = (_Float16)s2;
    o[3 * DIM] = (_Float16)s3;
}

// K2a: per-block (256-node chunk) sums over all replicas -> partial[SCAN_NB]
__global__ __launch_bounds__(256) void k_scan1(const unsigned* __restrict__ cnt2,
                                               unsigned* __restrict__ partial) {
    int t = threadIdx.x;
    int i = blockIdx.x * 256 + t;
    unsigned v = 0;
    if (i < N_NODES) {
        #pragma unroll
        for (int r = 0; r < NREP; ++r) v += cnt2[(size_t)r * N_NODES + i];
    }
    #pragma unroll
    for (int o = 32; o >= 1; o >>= 1) v += __shfl_xor(v, o, 64);
    __shared__ unsigned ws[4];
    if ((t & 63) == 0) ws[t >> 6] = v;
    __syncthreads();
    if (t == 0) partial[blockIdx.x] = ws[0] + ws[1] + ws[2] + ws[3];
}

// K2b: each block redundantly scans the 196 partials, then scans its own
// 256-node chunk -> off[i]; also emits per-replica bases off2[r*N+i].
__global__ __launch_bounds__(256) void k_scan23(const unsigned* __restrict__ cnt2,
                                                const unsigned* __restrict__ partial,
                                                unsigned* __restrict__ off,
                                                unsigned* __restrict__ off2) {
    int t = threadIdx.x;
    int lane = t & 63, w = t >> 6;
    __shared__ unsigned ws[4];
    __shared__ unsigned baseLds;
    unsigned pv = (t < SCAN_NB) ? partial[t] : 0u;
    unsigned inc = pv;
    #pragma unroll
    for (int d = 1; d < 64; d <<= 1) {
        unsigned u = __shfl_up(inc, d, 64);
        if (lane >= d) inc += u;
    }
    if (lane == 63) ws[w] = inc;
    __syncthreads();
    unsigned wadd = 0;
    #pragma unroll
    for (int k = 0; k < 4; ++k) if (k < w) wadd += ws[k];
    if (t == (int)blockIdx.x) baseLds = inc - pv + wadd;
    __syncthreads();
    unsigned base = baseLds;
    int i = blockIdx.x * 256 + t;
    unsigned c[NREP];
    unsigned v = 0;
    if (i < N_NODES) {
        #pragma unroll
        for (int r = 0; r < NREP; ++r) {
            c[r] = cnt2[(size_t)r * N_NODES + i];
            v += c[r];
        }
    }
    unsigned inc2 = v;
    #pragma unroll
    for (int d = 1; d < 64; d <<= 1) {
        unsigned u = __shfl_up(inc2, d, 64);
        if (lane >= d) inc2 += u;
    }
    __syncthreads();
    if (lane == 63) ws[w] = inc2;
    __syncthreads();
    unsigned wadd2 = 0;
    #pragma unroll
    for (int k = 0; k < 4; ++k) if (k < w) wadd2 += ws[k];
    if (i < N_NODES) {
        unsigned run = inc2 - v + wadd2 + base;
        off[i] = run;
        #pragma unroll
        for (int r = 0; r < NREP; ++r) {
            off2[(size_t)r * N_NODES + i] = run;
            run += c[r];
        }
    }
    if (blockIdx.x == 0 && t == 0) off[N_NODES] = N_EDGES;
}

// K3: scatter edges into CSR order (no atomics). Replica of edge e is
// recomputed from its histogram block: r = (XM_NB + e/1024) & 7.
__global__ __launch_bounds__(256) void k_scatter(const int* __restrict__ eidx,
                                                 const float* __restrict__ eattr,
                                                 const unsigned* __restrict__ off2,
                                                 const unsigned short* __restrict__ rank,
                                                 int2* __restrict__ elist) {
    int e = blockIdx.x * 256 + threadIdx.x;
    if (e >= N_EDGES) return;
    int dst = eidx[N_EDGES + e];
    int r = (XM_NB + (e >> 10)) & (NREP - 1);
    unsigned pos = off2[(size_t)r * N_NODES + dst] + rank[e];
    elist[pos] = make_int2(eidx[e], __float_as_int(eattr[e]));
}

// K4: wave per destination; 8 groups x 8 lanes; 8 edges per iteration.
__global__ __launch_bounds__(256) void k_aggregate(const half8* __restrict__ xm8,
                                                   const int2* __restrict__ elist,
                                                   const unsigned* __restrict__ off,
                                                   const float4* __restrict__ W_edge4,
                                                   const float4* __restrict__ att4,
                                                   const float4* __restrict__ x4,
                                                   float4* __restrict__ out4) {
    int node = blockIdx.x * 4 + (threadIdx.x >> 6);
    int lane = threadIdx.x & 63;
    int g = lane >> 3, t = lane & 7;
    unsigned beg = off[node], end = off[node + 1];
    size_t obase = (size_t)node * 16 + 2 * t;
    if (beg == end) {
        if (g == 0) { out4[obase] = x4[obase]; out4[obase + 1] = x4[obase + 1]; }
        return;
    }
    float4 wa = W_edge4[2 * t], wb = W_edge4[2 * t + 1];
    float4 aa = att4[2 * t],    ab = att4[2 * t + 1];
    float we[8] = {wa.x, wa.y, wa.z, wa.w, wb.x, wb.y, wb.z, wb.w};
    float at[8] = {aa.x, aa.y, aa.z, aa.w, ab.x, ab.y, ab.z, ab.w};

    unsigned idx = beg + (unsigned)g;
    bool act = idx < end;
    int2 e = elist[act ? idx : beg];
    half8 h = xm8[(size_t)e.x * 8 + t];

    float m = NEG_INF, denom = 0.f;
    float v[8];
    #pragma unroll
    for (int k = 0; k < 8; ++k) v[k] = 0.f;
    bool first = true;

    for (unsigned b = beg;; b += 8) {
        bool more = (b + 8) < end;         // wave-uniform
        int2 e2; half8 h2; bool a2 = false;
        if (more) {                        // prefetch next 8 edges
            unsigned i2 = b + 8 + (unsigned)g;
            a2 = i2 < end;
            e2 = elist[a2 ? i2 : beg];
            h2 = xm8[(size_t)e2.x * 8 + t];
        }
        float ea = __int_as_float(e.y);
        float msg[8];
        float p = 0.f;
        #pragma unroll
        for (int k = 0; k < 8; ++k) {
            float f = (float)h[k];
            msg[k] = fmaf(ea, we[k], f);
            float lr = fmaxf(msg[k], NEG_SLOPE * msg[k]);   // leaky (slope<1)
            p = fmaf(lr, at[k], p);
        }
        p += __shfl_xor(p, 1, 64);
        p += __shfl_xor(p, 2, 64);
        p += __shfl_xor(p, 4, 64);          // group-uniform logit
        if (first) {
            if (act) {
                m = p; denom = 1.f;
                #pragma unroll
                for (int k = 0; k < 8; ++k) v[k] = msg[k];
            }
            first = false;
        } else if (act) {
            float M = fmaxf(m, p);
            float so = __expf(m - M);
            float sn = __expf(p - M);
            denom = fmaf(denom, so, sn);
            #pragma unroll
            for (int k = 0; k < 8; ++k)
                v[k] = fmaxf(v[k] * so, msg[k] * sn);
            m = M;
        }
        if (!more) break;
        e = e2; h = h2; act = a2;
    }
    // merge the 8 per-group states
    bool has = denom > 0.f;
    float Ms = m;
    Ms = fmaxf(Ms, __shfl_xor(Ms, 8, 64));
    Ms = fmaxf(Ms, __shfl_xor(Ms, 16, 64));
    Ms = fmaxf(Ms, __shfl_xor(Ms, 32, 64));
    float s = has ? __expf(m - Ms) : 0.f;
    float dd = denom * s;
    dd += __shfl_xor(dd, 8, 64);
    dd += __shfl_xor(dd, 16, 64);
    dd += __shfl_xor(dd, 32, 64);
    float gv[8];
    #pragma unroll
    for (int k = 0; k < 8; ++k) {
        float gk = has ? v[k] * s : NEG_INF;
        gk = fmaxf(gk, __shfl_xor(gk, 8, 64));
        gk = fmaxf(gk, __shfl_xor(gk, 16, 64));
        gk = fmaxf(gk, __shfl_xor(gk, 32, 64));
        gv[k] = gk;
    }
    if (g == 0) {
        float inv = 1.0f / (dd + 1e-16f);
        float4 xa = x4[obase], xb = x4[obase + 1];
        float4 r0, r1;
        r0.x = fmaf(gv[0], inv, xa.x);
        r0.y = fmaf(gv[1], inv, xa.y);
        r0.z = fmaf(gv[2], inv, xa.z);
        r0.w = fmaf(gv[3], inv, xa.w);
        r1.x = fmaf(gv[4], inv, xb.x);
        r1.y = fmaf(gv[5], inv, xb.y);
        r1.z = fmaf(gv[6], inv, xb.z);
        r1.w = fmaf(gv[7], inv, xb.w);
        out4[obase] = r0;
        out4[obase + 1] = r1;
    }
}

extern "C" void kernel_launch(void* const* d_in, const int* in_sizes, int n_in,
                              void* d_out, int out_size, void* d_ws, size_t ws_size,
                              hipStream_t stream) {
    const float* x      = (const float*)d_in[0];
    const int*   eidx   = (const int*)d_in[1];     // [2, E] int32
    const float* eattr  = (const float*)d_in[2];
    const float* W_msg  = (const float*)d_in[3];
    const float* b_msg  = (const float*)d_in[4];
    const float* W_edge = (const float*)d_in[5];   // [1, D]
    const float* b_edge = (const float*)d_in[6];
    const float* att    = (const float*)d_in[7];
    float* out = (float*)d_out;

    // Workspace layout:
    //   xmh:     N*64 fp16    6.4 MB
    //   elist:   E int2       6.4 MB
    //   cnt2:    8N u32       1.6 MB  -- zeroed
    //   off:     N+1 u32
    //   off2:    8N u32       1.6 MB
    //   partial: SCAN_NB u32
    //   rank:    E u16        1.6 MB
    _Float16*       xmh     = (_Float16*)d_ws;
    int2*           elist   = (int2*)(xmh + (size_t)N_NODES * DIM);
    unsigned*       cnt2    = (unsigned*)(elist + N_EDGES);
    unsigned*       off     = cnt2 + (size_t)NREP * N_NODES;
    unsigned*       off2    = off + N_NODES + 1;
    unsigned*       partial = off2 + (size_t)NREP * N_NODES;
    unsigned short* rank    = (unsigned short*)(partial + SCAN_NB);

    hipMemsetAsync(cnt2, 0, (size_t)NREP * N_NODES * 4, stream);

    k_pre<<<XM_NB + CNT_NB, 256, 0, stream>>>(x, W_msg, b_msg, b_edge, xmh,
                                              eidx, cnt2, rank);
    k_scan1<<<SCAN_NB, 256, 0, stream>>>(cnt2, partial);
    k_scan23<<<SCAN_NB, 256, 0, stream>>>(cnt2, partial, off, off2);
    k_scatter<<<N_EDGES / 256, 256, 0, stream>>>(eidx, eattr, off2, rank, elist);
    k_aggregate<<<N_NODES / 4, 256, 0, stream>>>(
        (const half8*)xmh, elist, off, (const float4*)W_edge,
        (const float4*)att, (const float4*)x, (float4*)out);
}